// Round 5
// baseline (371.020 us; speedup 1.0000x reference)
//
#include <hip/hip_runtime.h>
#include <stdint.h>

typedef __bf16 bf16x8 __attribute__((ext_vector_type(8)));
typedef float f32x4 __attribute__((ext_vector_type(4)));

// ---- workspace byte offsets ----
#define OFF_ABF   0u           // pooled as bf16, per level [8192][C]
#define OFF_GWT   62914560u    // (g*W)^T bf16 per level [512][C]
#define OFF_H     66846720u    // h bf16 per level [8192][512]
#define OFF_STAT  100401152u   // per (l,row): sum, sumsq  (4*8192*2 f32)
#define OFF_TEXT  100663296u   // 4096 f32 normalized text
#define OFF_U     100679680u   // 4 lvl * 4 seg * 512 f32
#define OFF_GG    100712448u
#define OFF_BB    100745216u
#define OFF_SCAL  100777984u   // [0..3] sproto, [4..7] sqproto, [8] scale
#define WS_TOTAL  100778496u

__host__ __device__ __forceinline__ size_t abf_off(int l) {
  return (size_t)4194304u * (size_t)((1u << l) - 1u);
}
__host__ __device__ __forceinline__ size_t gwt_off(int l) {
  return (size_t)262144u * (size_t)((1u << l) - 1u);
}

__device__ __forceinline__ unsigned short f2bf(float x) {
  return (unsigned short)((__float_as_uint(x) + 0x8000u) >> 16);
}
__device__ __forceinline__ unsigned pack2(float a, float b) {
  return ((__float_as_uint(a) + 0x8000u) >> 16) |
         ((__float_as_uint(b) + 0x8000u) & 0xffff0000u);
}
__device__ __forceinline__ void async_load16(const void* g, void* l) {
  __builtin_amdgcn_global_load_lds((const __attribute__((address_space(1))) void*)g,
                                   (__attribute__((address_space(3))) void*)l,
                                   16, 0, 0);
}

struct PrepArgs {
  const float* pooled[4];
  const float* proto[4];
  const float* W[4];
  const float* g[4];
  const float* beta[4];
  const float* bias[4];
  const float* text;
  const float* lsc;
  char* ws;
};

// ================= aconv: standalone streaming convert + row stats =================
// One wave processes a 16 KB group = R rows x N4 float4/lane, all 16 loads in flight.
template <int N4, int R>
__device__ __forceinline__ void aconvG(const float* Pl, char* Ab, float* st,
                                       int C, int rowBase, int lane) {
  float4 v[R][N4];
  const float4* P0 = (const float4*)(Pl + (size_t)rowBase * C);
#pragma unroll
  for (int r = 0; r < R; ++r)
#pragma unroll
    for (int i = 0; i < N4; ++i)
      v[r][i] = P0[(size_t)r * (C >> 2) + lane + 64 * i];
#pragma unroll
  for (int r = 0; r < R; ++r) {
    uint2* D = (uint2*)(Ab + (size_t)(rowBase + r) * C * 2);
    float s1 = 0.f, s2 = 0.f;
#pragma unroll
    for (int i = 0; i < N4; ++i) {
      float4 x = v[r][i];
      s1 += x.x + x.y + x.z + x.w;
      s2 = fmaf(x.x, x.x, s2); s2 = fmaf(x.y, x.y, s2);
      s2 = fmaf(x.z, x.z, s2); s2 = fmaf(x.w, x.w, s2);
      uint2 o;
      o.x = pack2(x.x, x.y);
      o.y = pack2(x.z, x.w);
      D[lane + 64 * i] = o;
    }
#pragma unroll
    for (int off = 1; off < 64; off <<= 1) {
      s1 += __shfl_xor(s1, off);
      s2 += __shfl_xor(s2, off);
    }
    if (lane == 0) {
      st[(size_t)(rowBase + r) * 2] = s1;
      st[(size_t)(rowBase + r) * 2 + 1] = s2;
    }
  }
}

// groups of 16 KB: l3: 4096 (2 rows), l2: 2048 (4), l1: 1024 (8), l0: 512 (16) = 7680
__global__ __launch_bounds__(256, 4) void aconv(PrepArgs A) {
  int w = threadIdx.x >> 6, lane = threadIdx.x & 63;
  int waveId = blockIdx.x * 4 + w;
#pragma unroll 1
  for (int g = waveId * 2; g < waveId * 2 + 2; ++g) {
    int l, rowBase;
    if (g < 4096)      { l = 3; rowBase = g * 2; }
    else if (g < 6144) { l = 2; rowBase = (g - 4096) * 4; }
    else if (g < 7168) { l = 1; rowBase = (g - 6144) * 8; }
    else               { l = 0; rowBase = (g - 7168) * 16; }
    int C = 256 << l;
    const float* Pl = A.pooled[l];
    char* Ab = A.ws + OFF_ABF + abf_off(l);
    float* st = (float*)(A.ws + OFF_STAT) + (size_t)l * 8192 * 2;
    if (l == 3)      aconvG<8, 2>(Pl, Ab, st, C, rowBase, lane);
    else if (l == 2) aconvG<4, 4>(Pl, Ab, st, C, rowBase, lane);
    else if (l == 1) aconvG<2, 8>(Pl, Ab, st, C, rowBase, lane);
    else             aconvG<1, 16>(Pl, Ab, st, C, rowBase, lane);
  }
}

// ================= wprep: gwT build + u/G/B | proto sums | text =================
__global__ void wprep(PrepArgs A) {
  __shared__ unsigned short tile[64][72];
  __shared__ float r1[256], r2[256], r3[256];
  __shared__ float pm[1024];
  __shared__ float gsh[1024], bsh[1024];
  int t = threadIdx.x;
  int bid = blockIdx.x;

  if (bid < 128) {
    // ---- gwT build + u/G/B partials ----
    int l = 3 - (bid >> 5);
    int rem = bid & 31;
    int dchunk = rem >> 2, seg = rem & 3;
    int C = 256 << l, C2 = C * 2;
    int d0 = dchunk * 64;
    int dl = t & 63, jg = t >> 6;
    int d = d0 + dl;
    const float* W = A.W[l];
    const float* g = A.g[l];
    const float* beta = A.beta[l];
    unsigned short* gwT = (unsigned short*)(A.ws + OFF_GWT + gwt_off(l));
    int span = C2 >> 2;   // C/2
    int j0 = seg * span;
    bool top = (seg < 2);
    for (int i = t; i < span; i += 256) {
      gsh[i] = g[j0 + i];
      bsh[i] = beta[j0 + i];
    }
    if (!top) {
      const float* pr = A.proto[l];
      for (int c = t; c < span; c += 256) {
        const float* pp = pr + (j0 - C + c);
        float acc = 0.f;
#pragma unroll
        for (int r = 0; r < 64; ++r) acc += pp[(size_t)r * C];
        pm[c] = acc * (1.0f / 64.0f);
      }
    }
    __syncthreads();
    float gs = 0.f, bs = 0.f, uu = 0.f;
    for (int jc = j0; jc < j0 + span; jc += 64) {
      int jb = jc - j0;
      float wv[16];
#pragma unroll
      for (int u = 0; u < 16; ++u)
        wv[u] = W[(size_t)(jc + jg + 4 * u) * 512 + d];
#pragma unroll
      for (int u = 0; u < 16; ++u) {
        int jj = jg + 4 * u;
        float gw = gsh[jb + jj] * wv[u];
        gs += gw;
        bs = fmaf(bsh[jb + jj], wv[u], bs);
        if (top) tile[jj][dl] = f2bf(gw);
        else uu = fmaf(pm[jb + jj], gw, uu);
      }
      if (top) {
        __syncthreads();
        int dr = t >> 2, q4 = t & 3;
        unsigned o[8];
#pragma unroll
        for (int i = 0; i < 8; ++i) {
          unsigned lo = tile[q4 * 16 + 2 * i][dr];
          unsigned hi = tile[q4 * 16 + 2 * i + 1][dr];
          o[i] = lo | (hi << 16);
        }
        uint4* dst = (uint4*)(gwT + (size_t)(d0 + dr) * C + jc + q4 * 16);
        dst[0] = make_uint4(o[0], o[1], o[2], o[3]);
        dst[1] = make_uint4(o[4], o[5], o[6], o[7]);
        __syncthreads();
      }
    }
    r1[t] = gs; r2[t] = bs; r3[t] = uu;
    __syncthreads();
    if (t < 64) {
      float G = 0.f, Bv = 0.f, U = 0.f;
      for (int k = 0; k < 4; ++k) {
        G += r1[k * 64 + t];
        Bv += r2[k * 64 + t];
        U += r3[k * 64 + t];
      }
      if (seg == 0) Bv += A.bias[l][d0 + t];
      int idx = (l * 4 + seg) * 512 + d0 + t;
      ((float*)(A.ws + OFF_U))[idx] = U;
      ((float*)(A.ws + OFF_GG))[idx] = G;
      ((float*)(A.ws + OFF_BB))[idx] = Bv;
    }
  } else if (bid < 132) {
    // ---- per-level proto sums (sproto, sqproto) ----
    int l = bid - 128;
    int C = 256 << l;
    const float* pr = A.proto[l];
    float s1 = 0.f, s2 = 0.f;
    for (int c = t; c < C; c += 256) {
      const float* pp = pr + c;
      float acc = 0.f;
#pragma unroll
      for (int r = 0; r < 64; ++r) acc += pp[(size_t)r * C];
      float pmv = acc * (1.0f / 64.0f);
      s1 += pmv;
      s2 = fmaf(pmv, pmv, s2);
    }
    r1[t] = s1; r2[t] = s2;
    __syncthreads();
    for (int o = 128; o > 0; o >>= 1) {
      if (t < o) { r1[t] += r1[t + o]; r2[t] += r2[t + o]; }
      __syncthreads();
    }
    if (t == 0) {
      float* scal = (float*)(A.ws + OFF_SCAL);
      scal[l] = r1[0];
      scal[4 + l] = r2[0];
    }
  } else {
    // ---- text l2norm + scale ----
    float* tf = (float*)(A.ws + OFF_TEXT);
    for (int r = 0; r < 8; ++r) {
      float p = 0.f;
      for (int c = t; c < 512; c += 256) {
        float v = A.text[r * 512 + c];
        p += v * v;
      }
      r1[t] = p;
      __syncthreads();
      for (int o = 128; o > 0; o >>= 1) {
        if (t < o) r1[t] += r1[t + o];
        __syncthreads();
      }
      float inv = 1.0f / fmaxf(sqrtf(r1[0]), 1e-12f);
      __syncthreads();
      for (int c = t; c < 512; c += 256) tf[r * 512 + c] = A.text[r * 512 + c] * inv;
    }
    if (t == 0) {
      float s = fmaxf(A.lsc[0], 1e-4f);
      ((float*)(A.ws + OFF_SCAL))[8] = s * 0.04419417382415922f;  // 1/sqrt(512)
    }
  }
}

// ================= gemm2: m97-shape 128x128 bf16 GEMM + LN-fold epilogue =================
__global__ __launch_bounds__(256, 3) void gemm2(char* ws) {
  __shared__ __align__(16) char lds[18944];
  int t = threadIdx.x, bid = blockIdx.x;
  int l = 3 - (bid >> 8);          // heavy levels first
  int rb = (bid >> 2) & 63, cb = bid & 3;
  int C = 256 << l;
  int m0 = rb * 128, n0 = cb * 128;

  float* uArr  = (float*)(lds + 16384);
  float* gArr  = (float*)(lds + 16896);
  float* bArr  = (float*)(lds + 17408);
  float* rowM  = (float*)(lds + 17920);
  float* rowIS = (float*)(lds + 18432);
  const float* scal = (const float*)(ws + OFF_SCAL);

  if (t < 128) {
    float su = 0.f, sg = 0.f, sb = 0.f;
    for (int s = 0; s < 4; ++s) {
      int idx = (l * 4 + s) * 512 + n0 + t;
      su += ((const float*)(ws + OFF_U))[idx];
      sg += ((const float*)(ws + OFF_GG))[idx];
      sb += ((const float*)(ws + OFF_BB))[idx];
    }
    uArr[t] = su; gArr[t] = sg; bArr[t] = sb;
  } else {
    int r = t - 128;
    const float* st = (const float*)(ws + OFF_STAT) + (size_t)(l * 8192 + m0 + r) * 2;
    float s1 = st[0], s2 = st[1];
    float inv2C = 1.0f / (float)(2 * C);
    float mr = (s1 + scal[l]) * inv2C;
    float var = (s2 + scal[4 + l]) * inv2C - mr * mr;
    rowM[r] = mr;
    rowIS[r] = rsqrtf(var + 1e-5f);
  }

  int w = t >> 6, lane = t & 63, quad = lane >> 4, lc = lane & 15;
  const char* Abf = ws + OFF_ABF + abf_off(l);
  const char* Bw  = ws + OFF_GWT + gwt_off(l);
  const char* aP[2]; const char* bP[2];
  char* aD[2]; char* bD[2];
#pragma unroll
  for (int i = 0; i < 2; ++i) {
    int li = i * 256 + t;
    int rr = li >> 2, kq = li & 3;
    aP[i] = Abf + ((size_t)(m0 + rr) * C + kq * 8) * 2;
    bP[i] = Bw  + ((size_t)(n0 + rr) * C + kq * 8) * 2;
    aD[i] = lds + i * 4096 + w * 1024;
    bD[i] = lds + 8192 + i * 4096 + w * 1024;
  }
  int wr = (w >> 1) * 64, wc = (w & 1) * 64;
  const char* aF = lds + (wr + lc) * 64 + quad * 16;
  const char* bF = lds + 8192 + (wc + lc) * 64 + quad * 16;

  f32x4 acc[4][4] = {};
  for (int k0 = 0; k0 < C; k0 += 32) {
    async_load16(aP[0], aD[0]); async_load16(aP[1], aD[1]);
    async_load16(bP[0], bD[0]); async_load16(bP[1], bD[1]);
    aP[0] += 64; aP[1] += 64; bP[0] += 64; bP[1] += 64;
    __syncthreads();
    bf16x8 av[4];
#pragma unroll
    for (int rt = 0; rt < 4; ++rt) av[rt] = *(const bf16x8*)(aF + rt * 1024);
#pragma unroll
    for (int ct = 0; ct < 4; ++ct) {
      bf16x8 bv = *(const bf16x8*)(bF + ct * 1024);
#pragma unroll
      for (int rt = 0; rt < 4; ++rt)
        acc[rt][ct] = __builtin_amdgcn_mfma_f32_16x16x32_bf16(av[rt], bv, acc[rt][ct], 0, 0, 0);
    }
    __syncthreads();
  }

  // epilogue: h = relu((acc + u - m*G)*invs + B) -> bf16 store
  char* Hl = ws + OFF_H + (size_t)l * 8388608;
#pragma unroll
  for (int rt = 0; rt < 4; ++rt) {
#pragma unroll
    for (int ct = 0; ct < 4; ++ct) {
      int nl = wc + ct * 16 + lc;
      float uu = uArr[nl], gg = gArr[nl], bb = bArr[nl];
      f32x4 a = acc[rt][ct];
#pragma unroll
      for (int reg = 0; reg < 4; ++reg) {
        int ml = wr + rt * 16 + quad * 4 + reg;
        float h = fmaf(a[reg] + uu - rowM[ml] * gg, rowIS[ml], bb);
        h = fmaxf(h, 0.f);
        float hp = __shfl_xor(h, 1);
        if (!(lc & 1)) {
          unsigned pkv = pack2(h, hp);
          *(unsigned*)(Hl + ((size_t)(m0 + ml) * 512 + n0 + nl) * 2) = pkv;
        }
      }
    }
  }
}

// ================= postK: l2norm + text dots + softmax =================
__global__ __launch_bounds__(256) void postK(const char* ws, float* out) {
  __shared__ float textL[4096];
  int t = threadIdx.x, b = blockIdx.x;
  const float* tf = (const float*)(ws + OFF_TEXT);
  for (int i = t; i < 4096; i += 256) textL[i] = tf[i];
  __syncthreads();
  float scale = ((const float*)(ws + OFF_SCAL))[8];
  int row = b * 16 + (t >> 4), q = t & 15;
  float lg[4][8];
#pragma unroll
  for (int l = 0; l < 4; ++l) {
    const uint4* hp = (const uint4*)(ws + OFF_H + (size_t)l * 8388608 +
                                     ((size_t)row * 512 + q * 32) * 2);
    float np = 0.f;
    float dp[8] = {};
#pragma unroll
    for (int ch = 0; ch < 4; ++ch) {
      uint4 u = hp[ch];
      int d0 = q * 32 + ch * 8;
      unsigned uw[4] = {u.x, u.y, u.z, u.w};
#pragma unroll
      for (int p = 0; p < 4; ++p) {
        float v0 = __uint_as_float(uw[p] << 16);
        float v1 = __uint_as_float(uw[p] & 0xffff0000u);
        int dd = d0 + p * 2;
        np = fmaf(v0, v0, np);
        np = fmaf(v1, v1, np);
#pragma unroll
        for (int k = 0; k < 8; ++k) {
          dp[k] = fmaf(v0, textL[k * 512 + dd], dp[k]);
          dp[k] = fmaf(v1, textL[k * 512 + dd + 1], dp[k]);
        }
      }
    }
#pragma unroll
    for (int off = 1; off < 16; off <<= 1) {
      np += __shfl_xor(np, off);
#pragma unroll
      for (int k = 0; k < 8; ++k) dp[k] += __shfl_xor(dp[k], off);
    }
    float innorm = scale / fmaxf(sqrtf(np), 1e-12f);
#pragma unroll
    for (int k = 0; k < 8; ++k) lg[l][k] = dp[k] * innorm;
  }
  if (q == 0) {
    float4* op = (float4*)out + (size_t)row * 8;
#pragma unroll
    for (int k = 0; k < 8; ++k) {
      float a = lg[0][k], b2 = lg[1][k], c = lg[2][k], d = lg[3][k];
      float mx = fmaxf(fmaxf(a, b2), fmaxf(c, d));
      float e0 = __expf(a - mx), e1 = __expf(b2 - mx);
      float e2 = __expf(c - mx), e3 = __expf(d - mx);
      float inv = 1.0f / (e0 + e1 + e2 + e3);
      op[k] = make_float4(e0 * inv, e1 * inv, e2 * inv, e3 * inv);
    }
  }
}

extern "C" void kernel_launch(void* const* d_in, const int* in_sizes, int n_in,
                              void* d_out, int out_size, void* d_ws, size_t ws_size,
                              hipStream_t stream) {
  (void)n_in; (void)out_size;
  if (ws_size < (size_t)WS_TOTAL) return;  // loud failure: output stays poisoned
  char* ws = (char*)d_ws;
  bool dict = (in_sizes[1] == 64 * 256);
  PrepArgs pa;
  for (int l = 0; l < 4; ++l) {
    if (dict) {
      pa.pooled[l] = (const float*)d_in[6 * l + 0];
      pa.proto[l]  = (const float*)d_in[6 * l + 1];
      pa.g[l]      = (const float*)d_in[6 * l + 2];
      pa.beta[l]   = (const float*)d_in[6 * l + 3];
      pa.W[l]      = (const float*)d_in[6 * l + 4];
      pa.bias[l]   = (const float*)d_in[6 * l + 5];
    } else {
      pa.pooled[l] = (const float*)d_in[l];
      pa.proto[l]  = (const float*)d_in[4 + l];
      pa.g[l]      = (const float*)d_in[8 + l];
      pa.beta[l]   = (const float*)d_in[12 + l];
      pa.W[l]      = (const float*)d_in[16 + l];
      pa.bias[l]   = (const float*)d_in[20 + l];
    }
  }
  pa.text = (const float*)d_in[24];
  pa.lsc = (const float*)d_in[25];
  pa.ws = ws;

  aconv<<<960, 256, 0, stream>>>(pa);
  wprep<<<133, 256, 0, stream>>>(pa);
  gemm2<<<1024, 256, 0, stream>>>(ws);
  postK<<<512, 256, 0, stream>>>(ws, (float*)d_out);
}

// Round 6
// 299.992 us; speedup vs baseline: 1.2368x; 1.2368x over previous
//
#include <hip/hip_runtime.h>
#include <stdint.h>

typedef __bf16 bf16x8 __attribute__((ext_vector_type(8)));
typedef float f32x4 __attribute__((ext_vector_type(4)));

// ---- workspace byte offsets ----
#define OFF_ABF   0u           // pooled as bf16, per level [8192][C]
#define OFF_GWT   62914560u    // (g*W)^T bf16 per level [512][C]
#define OFF_H     66846720u    // h bf16 per level [8192][512]
#define OFF_STAT  100401152u   // per (l,row): sum, sumsq  (4*8192*2 f32)
#define OFF_TEXT  100663296u   // 4096 f32 normalized text
#define OFF_U     100679680u   // 4*512 f32 (zeroed, atomic-accumulated)
#define OFF_GG    100687872u
#define OFF_BB    100696064u
#define OFF_SCAL  100704256u   // [0..3] sproto, [4..7] sqproto, [8] scale (zeroed)
#define OFF_PMEAN 100704512u   // 3840 f32
#define WS_TOTAL  100719872u

__host__ __device__ __forceinline__ size_t abf_off(int l) {
  return (size_t)4194304u * (size_t)((1u << l) - 1u);
}
__host__ __device__ __forceinline__ size_t gwt_off(int l) {
  return (size_t)262144u * (size_t)((1u << l) - 1u);
}
__device__ __forceinline__ int pm_off(int l) { return 256 * ((1 << l) - 1); }

__device__ __forceinline__ unsigned short f2bf(float x) {
  return (unsigned short)((__float_as_uint(x) + 0x8000u) >> 16);
}
__device__ __forceinline__ unsigned pack2(float a, float b) {
  return ((__float_as_uint(a) + 0x8000u) >> 16) |
         ((__float_as_uint(b) + 0x8000u) & 0xffff0000u);
}
__device__ __forceinline__ void async_load16(const void* g, void* l) {
  __builtin_amdgcn_global_load_lds((const __attribute__((address_space(1))) void*)g,
                                   (__attribute__((address_space(3))) void*)l,
                                   16, 0, 0);
}

struct PrepArgs {
  const float* pooled[4];
  const float* proto[4];
  const float* W[4];
  const float* g[4];
  const float* beta[4];
  const float* bias[4];
  const float* text;
  const float* lsc;
  char* ws;
};

// ================= aconv (+ pmean + text): streaming convert + row stats =================
// One wave processes a 16 KB group = R rows x N4 float4/lane, all 16 loads in flight.
template <int N4, int R>
__device__ __forceinline__ void aconvG(const float* Pl, char* Ab, float* st,
                                       int C, int rowBase, int lane) {
  float4 v[R][N4];
  const float4* P0 = (const float4*)(Pl + (size_t)rowBase * C);
#pragma unroll
  for (int r = 0; r < R; ++r)
#pragma unroll
    for (int i = 0; i < N4; ++i)
      v[r][i] = P0[(size_t)r * (C >> 2) + lane + 64 * i];
#pragma unroll
  for (int r = 0; r < R; ++r) {
    uint2* D = (uint2*)(Ab + (size_t)(rowBase + r) * C * 2);
    float s1 = 0.f, s2 = 0.f;
#pragma unroll
    for (int i = 0; i < N4; ++i) {
      float4 x = v[r][i];
      s1 += x.x + x.y + x.z + x.w;
      s2 = fmaf(x.x, x.x, s2); s2 = fmaf(x.y, x.y, s2);
      s2 = fmaf(x.z, x.z, s2); s2 = fmaf(x.w, x.w, s2);
      uint2 o;
      o.x = pack2(x.x, x.y);
      o.y = pack2(x.z, x.w);
      D[lane + 64 * i] = o;
    }
#pragma unroll
    for (int off = 1; off < 64; off <<= 1) {
      s1 += __shfl_xor(s1, off);
      s2 += __shfl_xor(s2, off);
    }
    if (lane == 0) {
      st[(size_t)(rowBase + r) * 2] = s1;
      st[(size_t)(rowBase + r) * 2 + 1] = s2;
    }
  }
}

__global__ __launch_bounds__(256, 4) void aconv(PrepArgs A) {
  __shared__ float redP[4][64];
  int t = threadIdx.x, bid = blockIdx.x;
  int w = t >> 6, lane = t & 63;

  if (bid < 1920) {
    int g = bid * 4 + w;   // one 16 KB group per wave
    int l, rowBase;
    if (g < 4096)      { l = 3; rowBase = g * 2; }
    else if (g < 6144) { l = 2; rowBase = (g - 4096) * 4; }
    else if (g < 7168) { l = 1; rowBase = (g - 6144) * 8; }
    else               { l = 0; rowBase = (g - 7168) * 16; }
    int C = 256 << l;
    const float* Pl = A.pooled[l];
    char* Ab = A.ws + OFF_ABF + abf_off(l);
    float* st = (float*)(A.ws + OFF_STAT) + (size_t)l * 8192 * 2;
    if (l == 3)      aconvG<8, 2>(Pl, Ab, st, C, rowBase, lane);
    else if (l == 2) aconvG<4, 4>(Pl, Ab, st, C, rowBase, lane);
    else if (l == 1) aconvG<2, 8>(Pl, Ab, st, C, rowBase, lane);
    else             aconvG<1, 16>(Pl, Ab, st, C, rowBase, lane);
    return;
  }
  float* scal = (float*)(A.ws + OFF_SCAL);
  if (bid < 1980) {
    // ---- pmean (64-col chunks) + sproto/sqproto atomics ----
    int p = bid - 1920;
    int l, chunk;
    if (p < 32)      { l = 3; chunk = p; }
    else if (p < 48) { l = 2; chunk = p - 32; }
    else if (p < 56) { l = 1; chunk = p - 48; }
    else             { l = 0; chunk = p - 56; }
    int C = 256 << l;
    int c = chunk * 64 + lane;
    const float* pr = A.proto[l];
    float s = 0.f;
#pragma unroll
    for (int r = 0; r < 16; ++r) s += pr[(size_t)(w * 16 + r) * C + c];
    redP[w][lane] = s;
    __syncthreads();
    if (t < 64) {
      float pmv = (redP[0][t] + redP[1][t] + redP[2][t] + redP[3][t]) * (1.0f / 64.0f);
      ((float*)(A.ws + OFF_PMEAN))[pm_off(l) + chunk * 64 + t] = pmv;
      float s1 = pmv, s2 = pmv * pmv;
#pragma unroll
      for (int off = 1; off < 64; off <<= 1) {
        s1 += __shfl_xor(s1, off);
        s2 += __shfl_xor(s2, off);
      }
      if (t == 0) {
        atomicAdd(&scal[l], s1);
        atomicAdd(&scal[4 + l], s2);
      }
    }
    return;
  }
  // ---- text l2norm + scale ----
  float* r1 = &redP[0][0];
  float* tf = (float*)(A.ws + OFF_TEXT);
  for (int r = 0; r < 8; ++r) {
    float p = 0.f;
    for (int c = t; c < 512; c += 256) {
      float v = A.text[r * 512 + c];
      p += v * v;
    }
    r1[t] = p;
    __syncthreads();
    for (int o = 128; o > 0; o >>= 1) {
      if (t < o) r1[t] += r1[t + o];
      __syncthreads();
    }
    float inv = 1.0f / fmaxf(sqrtf(r1[0]), 1e-12f);
    __syncthreads();
    for (int c = t; c < 512; c += 256) tf[r * 512 + c] = A.text[r * 512 + c] * inv;
  }
  if (t == 0) {
    float s = fmaxf(A.lsc[0], 1e-4f);
    scal[8] = s * 0.04419417382415922f;  // 1/sqrt(512)
  }
}

// ================= wtrans: W-slab transpose + Gsum/Bsum/u partials =================
// 480 blocks, each a 64(j) x 128(d) slab. 16 independent float2 loads/lane.
__global__ __launch_bounds__(256) void wtrans(PrepArgs A) {
  __shared__ unsigned short tile[128][66];     // padded: 2-way-only banking
  __shared__ float redG[4][128], redB[4][128], redU[4][128];
  __shared__ float gsh[64], bsh[64], psh[64];
  int t = threadIdx.x, bid = blockIdx.x;
  int l, idl;
  if (bid < 256)      { l = 3; idl = bid; }
  else if (bid < 384) { l = 2; idl = bid - 256; }
  else if (bid < 448) { l = 1; idl = bid - 384; }
  else                { l = 0; idl = bid - 448; }
  int C = 256 << l;
  int sid = idl >> 2, dchunk = idl & 3;
  int j0 = sid * 64, d0 = dchunk * 128;
  bool top = (j0 < C);

  if (t < 64) {
    float gv = A.g[l][j0 + t];
    gsh[t] = gv;
    bsh[t] = A.beta[l][j0 + t];
    if (!top)
      psh[t] = ((const float*)(A.ws + OFF_PMEAN))[pm_off(l) + (j0 - C) + t] * gv;
  }
  __syncthreads();

  int w = t >> 6, L = t & 63;
  const float* W = A.W[l];
  float2 v[16];
#pragma unroll
  for (int r = 0; r < 16; ++r) {
    int j = j0 + w * 16 + r;
    v[r] = *(const float2*)(W + (size_t)j * 512 + d0 + 2 * L);
  }
  float gp0 = 0.f, gp1 = 0.f, bp0 = 0.f, bp1 = 0.f, up0 = 0.f, up1 = 0.f;
#pragma unroll
  for (int r = 0; r < 16; ++r) {
    int jl = w * 16 + r;
    float g = gsh[jl], b = bsh[jl];
    gp0 = fmaf(g, v[r].x, gp0); gp1 = fmaf(g, v[r].y, gp1);
    bp0 = fmaf(b, v[r].x, bp0); bp1 = fmaf(b, v[r].y, bp1);
    if (top) {
      tile[2 * L][jl] = f2bf(g * v[r].x);
      tile[2 * L + 1][jl] = f2bf(g * v[r].y);
    } else {
      float p = psh[jl];
      up0 = fmaf(p, v[r].x, up0); up1 = fmaf(p, v[r].y, up1);
    }
  }
  redG[w][2 * L] = gp0; redG[w][2 * L + 1] = gp1;
  redB[w][2 * L] = bp0; redB[w][2 * L + 1] = bp1;
  if (!top) { redU[w][2 * L] = up0; redU[w][2 * L + 1] = up1; }
  __syncthreads();

  if (t < 128) {
    int d = l * 512 + d0 + t;
    float G = redG[0][t] + redG[1][t] + redG[2][t] + redG[3][t];
    float B = redB[0][t] + redB[1][t] + redB[2][t] + redB[3][t];
    atomicAdd(&((float*)(A.ws + OFF_GG))[d], G);
    atomicAdd(&((float*)(A.ws + OFF_BB))[d], B);
    if (!top) {
      float U = redU[0][t] + redU[1][t] + redU[2][t] + redU[3][t];
      atomicAdd(&((float*)(A.ws + OFF_U))[d], U);
    }
  }
  if (top) {
    unsigned short* gwT = (unsigned short*)(A.ws + OFF_GWT + gwt_off(l));
    int d = t >> 1, jh = (t & 1) * 32;
    const unsigned* trow = (const unsigned*)&tile[d][jh];  // 4B-aligned
    uint4 a = make_uint4(trow[0], trow[1], trow[2], trow[3]);
    uint4 b = make_uint4(trow[4], trow[5], trow[6], trow[7]);
    uint4* dst = (uint4*)(gwT + (size_t)(d0 + d) * C + j0 + jh);
    dst[0] = a; dst[1] = b;
  }
}

// ================= gemm2: m97-shape 128x128 bf16 GEMM + LN-fold epilogue =================
struct G2Args {
  char* ws;
  const float* bias[4];
};

__global__ __launch_bounds__(256, 3) void gemm2(G2Args A) {
  __shared__ __align__(16) char lds[18944];
  char* ws = A.ws;
  int t = threadIdx.x, bid = blockIdx.x;
  int l = 3 - (bid >> 8);          // heavy levels first
  int rb = (bid >> 2) & 63, cb = bid & 3;
  int C = 256 << l;
  int m0 = rb * 128, n0 = cb * 128;

  float* uArr  = (float*)(lds + 16384);
  float* gArr  = (float*)(lds + 16896);
  float* bArr  = (float*)(lds + 17408);
  float* rowM  = (float*)(lds + 17920);
  float* rowIS = (float*)(lds + 18432);
  const float* scal = (const float*)(ws + OFF_SCAL);

  if (t < 128) {
    int idx = l * 512 + n0 + t;
    uArr[t] = ((const float*)(ws + OFF_U))[idx];
    gArr[t] = ((const float*)(ws + OFF_GG))[idx];
    bArr[t] = ((const float*)(ws + OFF_BB))[idx] + A.bias[l][n0 + t];
  } else {
    int r = t - 128;
    const float* st = (const float*)(ws + OFF_STAT) + (size_t)(l * 8192 + m0 + r) * 2;
    float s1 = st[0], s2 = st[1];
    float inv2C = 1.0f / (float)(2 * C);
    float mr = (s1 + scal[l]) * inv2C;
    float var = (s2 + scal[4 + l]) * inv2C - mr * mr;
    rowM[r] = mr;
    rowIS[r] = rsqrtf(var + 1e-5f);
  }

  int w = t >> 6, lane = t & 63, quad = lane >> 4, lc = lane & 15;
  const char* Abf = ws + OFF_ABF + abf_off(l);
  const char* Bw  = ws + OFF_GWT + gwt_off(l);
  const char* aP[2]; const char* bP[2];
  char* aD[2]; char* bD[2];
#pragma unroll
  for (int i = 0; i < 2; ++i) {
    int li = i * 256 + t;
    int rr = li >> 2, kq = li & 3;
    aP[i] = Abf + ((size_t)(m0 + rr) * C + kq * 8) * 2;
    bP[i] = Bw  + ((size_t)(n0 + rr) * C + kq * 8) * 2;
    aD[i] = lds + i * 4096 + w * 1024;
    bD[i] = lds + 8192 + i * 4096 + w * 1024;
  }
  int wr = (w >> 1) * 64, wc = (w & 1) * 64;
  const char* aF = lds + (wr + lc) * 64 + quad * 16;
  const char* bF = lds + 8192 + (wc + lc) * 64 + quad * 16;

  f32x4 acc[4][4] = {};
  for (int k0 = 0; k0 < C; k0 += 32) {
    async_load16(aP[0], aD[0]); async_load16(aP[1], aD[1]);
    async_load16(bP[0], bD[0]); async_load16(bP[1], bD[1]);
    aP[0] += 64; aP[1] += 64; bP[0] += 64; bP[1] += 64;
    __syncthreads();
    bf16x8 av[4];
#pragma unroll
    for (int rt = 0; rt < 4; ++rt) av[rt] = *(const bf16x8*)(aF + rt * 1024);
#pragma unroll
    for (int ct = 0; ct < 4; ++ct) {
      bf16x8 bv = *(const bf16x8*)(bF + ct * 1024);
#pragma unroll
      for (int rt = 0; rt < 4; ++rt)
        acc[rt][ct] = __builtin_amdgcn_mfma_f32_16x16x32_bf16(av[rt], bv, acc[rt][ct], 0, 0, 0);
    }
    __syncthreads();
  }

  // epilogue: h = relu((acc + u - m*G)*invs + B) -> bf16 store
  char* Hl = ws + OFF_H + (size_t)l * 8388608;
#pragma unroll
  for (int rt = 0; rt < 4; ++rt) {
#pragma unroll
    for (int ct = 0; ct < 4; ++ct) {
      int nl = wc + ct * 16 + lc;
      float uu = uArr[nl], gg = gArr[nl], bb = bArr[nl];
      f32x4 a = acc[rt][ct];
#pragma unroll
      for (int reg = 0; reg < 4; ++reg) {
        int ml = wr + rt * 16 + quad * 4 + reg;
        float h = fmaf(a[reg] + uu - rowM[ml] * gg, rowIS[ml], bb);
        h = fmaxf(h, 0.f);
        float hp = __shfl_xor(h, 1);
        if (!(lc & 1)) {
          unsigned pkv = pack2(h, hp);
          *(unsigned*)(Hl + ((size_t)(m0 + ml) * 512 + n0 + nl) * 2) = pkv;
        }
      }
    }
  }
}

// ================= postK: l2norm + text dots + softmax =================
__global__ __launch_bounds__(256) void postK(const char* ws, float* out) {
  __shared__ float textL[4096];
  int t = threadIdx.x, b = blockIdx.x;
  const float* tf = (const float*)(ws + OFF_TEXT);
  for (int i = t; i < 4096; i += 256) textL[i] = tf[i];
  __syncthreads();
  float scale = ((const float*)(ws + OFF_SCAL))[8];
  int row = b * 16 + (t >> 4), q = t & 15;
  float lg[4][8];
#pragma unroll
  for (int l = 0; l < 4; ++l) {
    const uint4* hp = (const uint4*)(ws + OFF_H + (size_t)l * 8388608 +
                                     ((size_t)row * 512 + q * 32) * 2);
    float np = 0.f;
    float dp[8] = {};
#pragma unroll
    for (int ch = 0; ch < 4; ++ch) {
      uint4 u = hp[ch];
      int d0 = q * 32 + ch * 8;
      unsigned uw[4] = {u.x, u.y, u.z, u.w};
#pragma unroll
      for (int p = 0; p < 4; ++p) {
        float v0 = __uint_as_float(uw[p] << 16);
        float v1 = __uint_as_float(uw[p] & 0xffff0000u);
        int dd = d0 + p * 2;
        np = fmaf(v0, v0, np);
        np = fmaf(v1, v1, np);
#pragma unroll
        for (int k = 0; k < 8; ++k) {
          dp[k] = fmaf(v0, textL[k * 512 + dd], dp[k]);
          dp[k] = fmaf(v1, textL[k * 512 + dd + 1], dp[k]);
        }
      }
    }
#pragma unroll
    for (int off = 1; off < 16; off <<= 1) {
      np += __shfl_xor(np, off);
#pragma unroll
      for (int k = 0; k < 8; ++k) dp[k] += __shfl_xor(dp[k], off);
    }
    float innorm = scale / fmaxf(sqrtf(np), 1e-12f);
#pragma unroll
    for (int k = 0; k < 8; ++k) lg[l][k] = dp[k] * innorm;
  }
  if (q == 0) {
    float4* op = (float4*)out + (size_t)row * 8;
#pragma unroll
    for (int k = 0; k < 8; ++k) {
      float a = lg[0][k], b2 = lg[1][k], c = lg[2][k], d = lg[3][k];
      float mx = fmaxf(fmaxf(a, b2), fmaxf(c, d));
      float e0 = __expf(a - mx), e1 = __expf(b2 - mx);
      float e2 = __expf(c - mx), e3 = __expf(d - mx);
      float inv = 1.0f / (e0 + e1 + e2 + e3);
      op[k] = make_float4(e0 * inv, e1 * inv, e2 * inv, e3 * inv);
    }
  }
}

extern "C" void kernel_launch(void* const* d_in, const int* in_sizes, int n_in,
                              void* d_out, int out_size, void* d_ws, size_t ws_size,
                              hipStream_t stream) {
  (void)n_in; (void)out_size;
  if (ws_size < (size_t)WS_TOTAL) return;  // loud failure: output stays poisoned
  char* ws = (char*)d_ws;
  bool dict = (in_sizes[1] == 64 * 256);
  PrepArgs pa;
  for (int l = 0; l < 4; ++l) {
    if (dict) {
      pa.pooled[l] = (const float*)d_in[6 * l + 0];
      pa.proto[l]  = (const float*)d_in[6 * l + 1];
      pa.g[l]      = (const float*)d_in[6 * l + 2];
      pa.beta[l]   = (const float*)d_in[6 * l + 3];
      pa.W[l]      = (const float*)d_in[6 * l + 4];
      pa.bias[l]   = (const float*)d_in[6 * l + 5];
    } else {
      pa.pooled[l] = (const float*)d_in[l];
      pa.proto[l]  = (const float*)d_in[4 + l];
      pa.g[l]      = (const float*)d_in[8 + l];
      pa.beta[l]   = (const float*)d_in[12 + l];
      pa.W[l]      = (const float*)d_in[16 + l];
      pa.bias[l]   = (const float*)d_in[20 + l];
    }
  }
  pa.text = (const float*)d_in[24];
  pa.lsc = (const float*)d_in[25];
  pa.ws = ws;

  // zero the atomic accumulators (U/GG/BB/SCAL are contiguous)
  hipMemsetAsync(ws + OFF_U, 0, 3 * 8192 + 256, stream);
  aconv<<<1981, 256, 0, stream>>>(pa);
  wtrans<<<480, 256, 0, stream>>>(pa);

  G2Args g2;
  g2.ws = ws;
  for (int l = 0; l < 4; ++l) g2.bias[l] = pa.bias[l];
  gemm2<<<1024, 256, 0, stream>>>(g2);
  postK<<<512, 256, 0, stream>>>(ws, (float*)d_out);
}